// Round 1
// baseline (916.362 us; speedup 1.0000x reference)
//
#include <hip/hip_runtime.h>
#include <hip/hip_bf16.h>

// Fused 3D shifted-window attention for MI355X (gfx950).
// One block = one window (98 tokens, padded to 112 rows for 16x16x32 MFMA).
// Phases: [0] offsets+zeroing | [1a] gather x -> LDS (bf16, frag order)
//         [1b] QKV GEMM (MFMA) -> Q,K,V in LDS | [2] per-(head,mtile) flash
//         attention (S MFMA, reg softmax, P->LDS transpose, PV MFMA) -> O
//         | [3] proj GEMM (MFMA) -> scatter fp32 to d_out.
// Weights pre-converted to bf16 in d_ws by cvt_weights_kernel (73 KB).

typedef __attribute__((ext_vector_type(8))) short short8;   // 8 bf16 = 4 VGPR
typedef __attribute__((ext_vector_type(4))) float f32x4;    // MFMA acc

#define WQ_ELEMS (288 * 96)
#define WP_ELEMS (96 * 96)

__device__ __forceinline__ unsigned short f2bf(float f) {
  __hip_bfloat16 h = __float2bfloat16(f);
  return *reinterpret_cast<unsigned short*>(&h);
}

__global__ __launch_bounds__(256) void cvt_weights_kernel(
    const float* __restrict__ qkv_w, const float* __restrict__ proj_w,
    unsigned short* __restrict__ wq, unsigned short* __restrict__ wp) {
  int i = blockIdx.x * 256 + threadIdx.x;
  if (i < WQ_ELEMS) wq[i] = f2bf(qkv_w[i]);
  if (i < WP_ELEMS) wp[i] = f2bf(proj_w[i]);
}

// LDS element offsets (ushort units):
//   Qf   [12 cb][112 tok][8]  : 10752   (ch-block cb = channel/8)
//   Kf   same                 : 10752
//   Vtf  [16 tb][96 ch][8]    : 12288   (tok-block tb = token/8; tb 14,15 zero)
//   XO   [12 cb][112 tok][8]  : 10752   (X during QKV, attn-out O afterwards)
//   Pw   4 waves x [16 kb][16 m][8] : 8192  (per-wave P in A-frag order)
// total 52736 ushorts = 105472 B  + eoff[112] ints = 105920 B LDS.

__global__ __launch_bounds__(256) void winattn_kernel(
    const float* __restrict__ x, const float* __restrict__ qkv_b,
    const float* __restrict__ proj_b, const float* __restrict__ tbl,
    const unsigned short* __restrict__ wq, const unsigned short* __restrict__ wp,
    float* __restrict__ out) {

  __shared__ __align__(16) unsigned short lds[52736];
  __shared__ int eoff[112];

  unsigned short* Qf  = lds;
  unsigned short* Kf  = lds + 10752;
  unsigned short* Vtf = lds + 21504;
  unsigned short* XO  = lds + 33792;
  unsigned short* Pw  = lds + 44544;

  const int tid  = threadIdx.x;
  const int wv   = tid >> 6;
  const int lane = tid & 63;
  const int l    = lane & 15;   // MFMA: A/B non-K index, C col
  const int q    = lane >> 4;   // MFMA: quad (k-chunk for A/B, row-group for C)

  // ---- window decode: flat order (B, d0=1, d1, d2, S'=4, H'=8, W'=8) ----
  int t1 = blockIdx.x;
  const int wb = t1 & 7;  t1 >>= 3;
  const int hb = t1 & 7;  t1 >>= 3;
  const int sb = t1 & 3;  t1 >>= 2;
  const int d2 = t1 & 1;  t1 >>= 1;
  const int d1 = t1 & 1;  t1 >>= 1;
  const int b  = t1;

  // ---- phase 0: zero P pad region, V token-pad blocks; token offsets ----
  for (int i = tid; i < 8192; i += 256) Pw[i] = 0;          // kb 14,15 stay 0
  for (int i = tid; i < 1536; i += 256) Vtf[10752 + i] = 0; // tokens 112..127
  if (tid < 112) {
    int e = 0;
    if (tid < 98) {
      int wi0 = tid / 49; int r = tid - wi0 * 49;
      int wi1 = r / 7;    int wi2 = r - wi1 * 7;
      int s  = sb * 2 + wi0;            int so = (s + 1) & 7;
      int hh = (hb * 2 + d1) * 7 + wi1; int ho = hh + 6; if (ho >= 112) ho -= 112;
      int ww = (wb * 2 + d2) * 7 + wi2; int wo = ww + 6; if (wo >= 112) wo -= 112;
      e = (b * 100352 + (so * 112 + ho) * 112 + wo) * 96;
    }
    eoff[tid] = e;
  }
  __syncthreads();

  // ---- phase 1a: gather x rows -> XO (bf16, fragment order), pad rows 0 ----
  for (int i = tid; i < 112 * 24; i += 256) {
    int row = i / 24, c4 = i - row * 24;     // c4: which float4 of the 96 ch
    float4 v = make_float4(0.f, 0.f, 0.f, 0.f);
    if (row < 98) v = *reinterpret_cast<const float4*>(x + eoff[row] + c4 * 4);
    ushort4 u;
    u.x = f2bf(v.x); u.y = f2bf(v.y); u.z = f2bf(v.z); u.w = f2bf(v.w);
    *reinterpret_cast<ushort4*>(&XO[((c4 >> 1) * 112 + row) * 8 + (c4 & 1) * 4]) = u;
  }
  __syncthreads();

  // ---- phase 1b: QKV = X(112x96) @ Wqkv^T(96x288) + b ----
  const float scale = 0.17677669529663687f;   // 32^-0.5
  for (int t = wv; t < 126; t += 4) {         // 18 n-tiles x 7 m-tiles
    int nt = t / 7, mt = t - nt * 7;
    int n = nt * 16 + l;                      // output channel (0..287)
    short8 b0 = *reinterpret_cast<const short8*>(wq + n * 96 +      q * 8);
    short8 b1 = *reinterpret_cast<const short8*>(wq + n * 96 + 32 + q * 8);
    short8 b2 = *reinterpret_cast<const short8*>(wq + n * 96 + 64 + q * 8);
    short8 a0 = *reinterpret_cast<const short8*>(&XO[(( q     ) * 112 + mt * 16 + l) * 8]);
    short8 a1 = *reinterpret_cast<const short8*>(&XO[((4 + q  ) * 112 + mt * 16 + l) * 8]);
    short8 a2 = *reinterpret_cast<const short8*>(&XO[((8 + q  ) * 112 + mt * 16 + l) * 8]);
    f32x4 acc = {0.f, 0.f, 0.f, 0.f};
    acc = __builtin_amdgcn_mfma_f32_16x16x32_bf16(a0, b0, acc, 0, 0, 0);
    acc = __builtin_amdgcn_mfma_f32_16x16x32_bf16(a1, b1, acc, 0, 0, 0);
    acc = __builtin_amdgcn_mfma_f32_16x16x32_bf16(a2, b2, acc, 0, 0, 0);
    float bias = qkv_b[n];
#pragma unroll
    for (int r = 0; r < 4; r++) {
      int tok = mt * 16 + q * 4 + r;          // C layout: row = quad*4+reg
      float v = acc[r] + bias;
      if (n < 96) {                           // Q (pre-scaled)
        v *= scale;
        Qf[((n >> 3) * 112 + tok) * 8 + (n & 7)] = f2bf(v);
      } else if (n < 192) {                   // K
        int ch = n - 96;
        Kf[((ch >> 3) * 112 + tok) * 8 + (ch & 7)] = f2bf(v);
      } else {                                // V, transposed (token-blocked)
        int ch = n - 192;
        Vtf[((tok >> 3) * 96 + ch) * 8 + (tok & 7)] = f2bf(v);
      }
    }
  }
  __syncthreads();

  // ---- phase 2: flash attention, one (head, m-tile) per wave-iteration ----
  unsigned short* PwW = Pw + wv * 2048;
  for (int p = wv; p < 21; p += 4) {
    int h = p / 7, mt = p - h * 7;
    short8 qa = *reinterpret_cast<const short8*>(&Qf[((h * 4 + q) * 112 + mt * 16 + l) * 8]);
    f32x4 s[7];
#pragma unroll
    for (int nt = 0; nt < 7; nt++) {
      short8 kb = *reinterpret_cast<const short8*>(&Kf[((h * 4 + q) * 112 + nt * 16 + l) * 8]);
      f32x4 z = {0.f, 0.f, 0.f, 0.f};
      s[nt] = __builtin_amdgcn_mfma_f32_16x16x32_bf16(qa, kb, z, 0, 0, 0);
    }
    // relative-position bias (+ mask cols >= 98)
    int a0c[4], a1c[4], a2c[4];
#pragma unroll
    for (int r = 0; r < 4; r++) {
      int m = mt * 16 + q * 4 + r; if (m > 97) m = 97;
      a0c[r] = m / 49; int rr = m - a0c[r] * 49;
      a1c[r] = rr / 7; a2c[r] = rr - a1c[r] * 7;
    }
#pragma unroll
    for (int nt = 0; nt < 7; nt++) {
      int col = nt * 16 + l;
      if (col < 98) {
        int b0c = col / 49; int rr = col - b0c * 49;
        int b1c = rr / 7;   int b2c = rr - b1c * 7;
#pragma unroll
        for (int r = 0; r < 4; r++) {
          int idx = (a0c[r] - b0c + 1) * 169 + (a1c[r] - b1c + 6) * 13 + (a2c[r] - b2c + 6);
          s[nt][r] += tbl[idx * 3 + h];
        }
      } else {
#pragma unroll
        for (int r = 0; r < 4; r++) s[nt][r] = -1e30f;
      }
    }
    // softmax over the 112-wide row: reduce across 16 lanes of the quad
    float mx[4] = {-1e30f, -1e30f, -1e30f, -1e30f};
#pragma unroll
    for (int nt = 0; nt < 7; nt++)
#pragma unroll
      for (int r = 0; r < 4; r++) mx[r] = fmaxf(mx[r], s[nt][r]);
#pragma unroll
    for (int off = 1; off <= 8; off <<= 1)
#pragma unroll
      for (int r = 0; r < 4; r++) mx[r] = fmaxf(mx[r], __shfl_xor(mx[r], off, 64));
    float sum[4] = {0.f, 0.f, 0.f, 0.f};
#pragma unroll
    for (int nt = 0; nt < 7; nt++)
#pragma unroll
      for (int r = 0; r < 4; r++) {
        float e = __expf(s[nt][r] - mx[r]);
        s[nt][r] = e; sum[r] += e;
      }
#pragma unroll
    for (int off = 1; off <= 8; off <<= 1)
#pragma unroll
      for (int r = 0; r < 4; r++) sum[r] += __shfl_xor(sum[r], off, 64);
    float inv[4];
#pragma unroll
    for (int r = 0; r < 4; r++) inv[r] = 1.0f / sum[r];
    // transpose P (C layout -> A layout) through per-wave LDS
#pragma unroll
    for (int nt = 0; nt < 7; nt++) {
      int colk = nt * 16 + l; int kb_ = colk >> 3; int j = colk & 7;
#pragma unroll
      for (int r = 0; r < 4; r++)
        PwW[(kb_ * 16 + q * 4 + r) * 8 + j] = f2bf(s[nt][r] * inv[r]);
    }
    asm volatile("s_waitcnt lgkmcnt(0)" ::: "memory");
    // PV: O(16x32) = P(16x128) @ V(128x32), K padded to 128 with zeros
    f32x4 o0 = {0.f, 0.f, 0.f, 0.f}, o1 = {0.f, 0.f, 0.f, 0.f};
#pragma unroll
    for (int kt = 0; kt < 4; kt++) {
      short8 pa = *reinterpret_cast<const short8*>(&PwW[((kt * 4 + q) * 16 + l) * 8]);
      short8 v0 = *reinterpret_cast<const short8*>(&Vtf[((kt * 4 + q) * 96 + h * 32 + l) * 8]);
      short8 v1 = *reinterpret_cast<const short8*>(&Vtf[((kt * 4 + q) * 96 + h * 32 + 16 + l) * 8]);
      o0 = __builtin_amdgcn_mfma_f32_16x16x32_bf16(pa, v0, o0, 0, 0, 0);
      o1 = __builtin_amdgcn_mfma_f32_16x16x32_bf16(pa, v1, o1, 0, 0, 0);
    }
#pragma unroll
    for (int r = 0; r < 4; r++) {
      int tok = mt * 16 + q * 4 + r;
      int ch0 = h * 32 + l;
      XO[((ch0 >> 3) * 112 + tok) * 8 + (ch0 & 7)] = f2bf(o0[r]);
      int ch1 = h * 32 + 16 + l;
      XO[((ch1 >> 3) * 112 + tok) * 8 + (ch1 & 7)] = f2bf(o1[r]);
    }
  }
  __syncthreads();

  // ---- phase 3: proj = O(112x96) @ Wp^T(96x96) + b, scatter fp32 ----
  for (int t = wv; t < 42; t += 4) {          // 6 n-tiles x 7 m-tiles
    int nt = t / 7, mt = t - nt * 7;
    int n = nt * 16 + l;
    short8 b0 = *reinterpret_cast<const short8*>(wp + n * 96 +      q * 8);
    short8 b1 = *reinterpret_cast<const short8*>(wp + n * 96 + 32 + q * 8);
    short8 b2 = *reinterpret_cast<const short8*>(wp + n * 96 + 64 + q * 8);
    short8 a0 = *reinterpret_cast<const short8*>(&XO[(( q    ) * 112 + mt * 16 + l) * 8]);
    short8 a1 = *reinterpret_cast<const short8*>(&XO[((4 + q ) * 112 + mt * 16 + l) * 8]);
    short8 a2 = *reinterpret_cast<const short8*>(&XO[((8 + q ) * 112 + mt * 16 + l) * 8]);
    f32x4 acc = {0.f, 0.f, 0.f, 0.f};
    acc = __builtin_amdgcn_mfma_f32_16x16x32_bf16(a0, b0, acc, 0, 0, 0);
    acc = __builtin_amdgcn_mfma_f32_16x16x32_bf16(a1, b1, acc, 0, 0, 0);
    acc = __builtin_amdgcn_mfma_f32_16x16x32_bf16(a2, b2, acc, 0, 0, 0);
    float pb = proj_b[n];
#pragma unroll
    for (int r = 0; r < 4; r++) {
      int tok = mt * 16 + q * 4 + r;
      if (tok < 98) out[eoff[tok] + n] = acc[r] + pb;
    }
  }
}

extern "C" void kernel_launch(void* const* d_in, const int* in_sizes, int n_in,
                              void* d_out, int out_size, void* d_ws, size_t ws_size,
                              hipStream_t stream) {
  const float* x      = (const float*)d_in[0];
  const float* qkv_w  = (const float*)d_in[1];
  const float* qkv_b  = (const float*)d_in[2];
  const float* proj_w = (const float*)d_in[3];
  const float* proj_b = (const float*)d_in[4];
  const float* tbl    = (const float*)d_in[5];

  unsigned short* wq = (unsigned short*)d_ws;
  unsigned short* wp = wq + WQ_ELEMS;

  cvt_weights_kernel<<<(WQ_ELEMS + 255) / 256, 256, 0, stream>>>(qkv_w, proj_w, wq, wp);
  winattn_kernel<<<4096, 256, 0, stream>>>(x, qkv_b, proj_b, tbl, wq, wp,
                                           (float*)d_out);
}

// Round 2
// 614.433 us; speedup vs baseline: 1.4914x; 1.4914x over previous
//
#include <hip/hip_runtime.h>
#include <hip/hip_bf16.h>

// Fused 3D shifted-window attention for MI355X (gfx950).
// One block = one window (98 tokens, stored rows padded only to 98; MFMA
// m-tiles padded to 112 via zeroed register fragments).
// LDS budget 81416 B -> 2 blocks/CU (the round-1 kernel was 106 KB -> 1
// block/CU -> 11.9% occupancy, all pipes idle).
// Phases: [0] offsets + V-pad zeroing | [1a] gather x -> Xf (bf16 frag order)
//         [1b] QKV GEMM -> Q,K,V LDS | [2] per-(head,mtile) attention:
//         S MFMA + precomputed-bias load + reg softmax + P transpose via
//         per-wave LDS (overlaid on dead X) + PV MFMA; O overwrites Q slot
//         | [3] proj GEMM -> scatter fp32 to d_out.
// prep_kernel: weights -> bf16, full [3][112][112] rel-bias tensor (150 KB,
// L2/L3 resident, removes 28 data-dependent gathers + div chains per iter).

typedef __attribute__((ext_vector_type(8))) short short8;   // 8 bf16 = 4 VGPR
typedef __attribute__((ext_vector_type(4))) float f32x4;    // MFMA acc

#define WQ_ELEMS (288 * 96)
#define WP_ELEMS (96 * 96)
#define BIAS_ELEMS (3 * 112 * 112)

__device__ __forceinline__ unsigned short f2bf(float f) {
  __hip_bfloat16 h = __float2bfloat16(f);
  return *reinterpret_cast<unsigned short*>(&h);
}

__global__ __launch_bounds__(256) void prep_kernel(
    const float* __restrict__ qkv_w, const float* __restrict__ proj_w,
    const float* __restrict__ tbl, unsigned short* __restrict__ wq,
    unsigned short* __restrict__ wp, float* __restrict__ bias) {
  int i = blockIdx.x * 256 + threadIdx.x;
  if (i < WQ_ELEMS) wq[i] = f2bf(qkv_w[i]);
  if (i < WP_ELEMS) wp[i] = f2bf(proj_w[i]);
  if (i < BIAS_ELEMS) {
    int h = i / 12544; int rem = i - h * 12544;
    int m = rem / 112; int n = rem - m * 112;
    float v = 0.f;
    if (m < 98 && n < 98) {
      int m0 = m / 49, mr = m - m0 * 49, m1 = mr / 7, m2 = mr - m1 * 7;
      int n0 = n / 49, nr = n - n0 * 49, n1 = nr / 7, n2 = nr - n1 * 7;
      int idx = (m0 - n0 + 1) * 169 + (m1 - n1 + 6) * 13 + (m2 - n2 + 6);
      v = tbl[idx * 3 + h];
    }
    bias[i] = v;
  }
}

// LDS (ushort units):
//   Qf/O [12 cb][98 tok][8] : 9408  @ 0      (O overwrites Q in-place)
//   Kf   [12 cb][98 tok][8] : 9408  @ 9408
//   Vtf  [16 tb][96 ch][8]  : 12288 @ 18816  (tokens 98..127 zeroed)
//   Xf/P [12 cb][98][8]=9408 vs 4 waves x [16 m][136 k]=8704 -> 9408 @ 31104
// total 40512 us = 81024 B + eoff[98] = 81416 B  (<= 81920 -> 2 blocks/CU)

__global__ __launch_bounds__(256) void winattn_kernel(
    const float* __restrict__ x, const float* __restrict__ qkv_b,
    const float* __restrict__ proj_b, const unsigned short* __restrict__ wq,
    const unsigned short* __restrict__ wp, const float* __restrict__ bias,
    float* __restrict__ out) {

  __shared__ __align__(16) unsigned short lds[40512];
  __shared__ int eoff[98];

  unsigned short* Qf  = lds;          // also O
  unsigned short* Kf  = lds + 9408;
  unsigned short* Vtf = lds + 18816;
  unsigned short* Xf  = lds + 31104;  // also P (per-wave)

  const int tid  = threadIdx.x;
  const int wv   = tid >> 6;
  const int lane = tid & 63;
  const int l    = lane & 15;   // MFMA: A/B non-K index, C col
  const int q    = lane >> 4;   // MFMA: quad

  const short8 zero8 = {0, 0, 0, 0, 0, 0, 0, 0};

  // ---- window decode: flat order (B, d0=1, d1, d2, S'=4, H'=8, W'=8) ----
  int t1 = blockIdx.x;
  const int wb = t1 & 7;  t1 >>= 3;
  const int hb = t1 & 7;  t1 >>= 3;
  const int sb = t1 & 3;  t1 >>= 2;
  const int d2 = t1 & 1;  t1 >>= 1;
  const int d1 = t1 & 1;  t1 >>= 1;
  const int b  = t1;

  // ---- phase 0: zero V token-pad blocks (tb 12..15); token offsets ----
  for (int i = tid; i < 3072; i += 256) Vtf[9216 + i] = 0;
  if (tid < 98) {
    int wi0 = tid / 49; int r = tid - wi0 * 49;
    int wi1 = r / 7;    int wi2 = r - wi1 * 7;
    int s  = sb * 2 + wi0;            int so = (s + 1) & 7;
    int hh = (hb * 2 + d1) * 7 + wi1; int ho = hh + 6; if (ho >= 112) ho -= 112;
    int ww = (wb * 2 + d2) * 7 + wi2; int wo = ww + 6; if (wo >= 112) wo -= 112;
    eoff[tid] = (b * 100352 + (so * 112 + ho) * 112 + wo) * 96;
  }
  __syncthreads();

  // ---- phase 1a: gather x rows -> Xf (bf16, fragment order) ----
  for (int i = tid; i < 98 * 24; i += 256) {
    int row = i / 24, c4 = i - row * 24;     // c4: which float4 of 96 ch
    float4 v = *reinterpret_cast<const float4*>(x + eoff[row] + c4 * 4);
    ushort4 u;
    u.x = f2bf(v.x); u.y = f2bf(v.y); u.z = f2bf(v.z); u.w = f2bf(v.w);
    *reinterpret_cast<ushort4*>(&Xf[((c4 >> 1) * 98 + row) * 8 + (c4 & 1) * 4]) = u;
  }
  __syncthreads();

  // ---- phase 1b: QKV = X(98x96) @ Wqkv^T(96x288) + b ----
  const float scale = 0.17677669529663687f;   // 32^-0.5
  for (int t = wv; t < 126; t += 4) {         // 18 n-tiles x 7 m-tiles
    int nt = t / 7, mt = t - nt * 7;
    int n = nt * 16 + l;                      // output channel (0..287)
    short8 b0 = *reinterpret_cast<const short8*>(wq + n * 96 +      q * 8);
    short8 b1 = *reinterpret_cast<const short8*>(wq + n * 96 + 32 + q * 8);
    short8 b2 = *reinterpret_cast<const short8*>(wq + n * 96 + 64 + q * 8);
    int arow = mt * 16 + l;
    short8 a0 = zero8, a1 = zero8, a2 = zero8;
    if (arow < 98) {
      a0 = *reinterpret_cast<const short8*>(&Xf[(( q     ) * 98 + arow) * 8]);
      a1 = *reinterpret_cast<const short8*>(&Xf[((4 + q  ) * 98 + arow) * 8]);
      a2 = *reinterpret_cast<const short8*>(&Xf[((8 + q  ) * 98 + arow) * 8]);
    }
    f32x4 acc = {0.f, 0.f, 0.f, 0.f};
    acc = __builtin_amdgcn_mfma_f32_16x16x32_bf16(a0, b0, acc, 0, 0, 0);
    acc = __builtin_amdgcn_mfma_f32_16x16x32_bf16(a1, b1, acc, 0, 0, 0);
    acc = __builtin_amdgcn_mfma_f32_16x16x32_bf16(a2, b2, acc, 0, 0, 0);
    float bv = qkv_b[n];
#pragma unroll
    for (int r = 0; r < 4; r++) {
      int tok = mt * 16 + q * 4 + r;          // C layout: row = quad*4+reg
      if (tok < 98) {
        float v = acc[r] + bv;
        if (n < 96) {                         // Q (pre-scaled)
          v *= scale;
          Qf[((n >> 3) * 98 + tok) * 8 + (n & 7)] = f2bf(v);
        } else if (n < 192) {                 // K
          int ch = n - 96;
          Kf[((ch >> 3) * 98 + tok) * 8 + (ch & 7)] = f2bf(v);
        } else {                              // V, transposed (token-blocked)
          int ch = n - 192;
          Vtf[((tok >> 3) * 96 + ch) * 8 + (tok & 7)] = f2bf(v);
        }
      }
    }
  }
  __syncthreads();

  // ---- phase 2: attention, one (head, m-tile) per wave-iteration ----
  unsigned short* PwW = Xf + wv * 2176;       // [16 m][136]: 128 k + 8 pad
  {                                           // zero P cols 112..127 once
    int m = lane >> 2, c0 = 112 + (lane & 3) * 4;
    ushort4 z4 = {0, 0, 0, 0};
    *reinterpret_cast<ushort4*>(&PwW[m * 136 + c0]) = z4;
  }
  for (int p = wv; p < 21; p += 4) {
    int h = p / 7, mt = p - h * 7;
    int qrow = mt * 16 + l;
    short8 qa = zero8;
    if (qrow < 98)
      qa = *reinterpret_cast<const short8*>(&Qf[((h * 4 + q) * 98 + qrow) * 8]);
    f32x4 s[7];
#pragma unroll
    for (int nt = 0; nt < 7; nt++) {
      int col = nt * 16 + l;
      short8 kb = zero8;
      if (col < 98)
        kb = *reinterpret_cast<const short8*>(&Kf[((h * 4 + q) * 98 + col) * 8]);
      f32x4 z = {0.f, 0.f, 0.f, 0.f};
      s[nt] = __builtin_amdgcn_mfma_f32_16x16x32_bf16(qa, kb, z, 0, 0, 0);
    }
    // precomputed relative-position bias, then mask cols >= 98
    const float* bh = bias + h * 12544 + (mt * 16 + q * 4) * 112;
#pragma unroll
    for (int nt = 0; nt < 7; nt++) {
      int col = nt * 16 + l;
      if (col < 98) {
#pragma unroll
        for (int r = 0; r < 4; r++) s[nt][r] += bh[r * 112 + col];
      } else {
#pragma unroll
        for (int r = 0; r < 4; r++) s[nt][r] = -1e30f;
      }
    }
    // softmax over the 112-wide row: reduce across 16 lanes of the quad
    float mx[4] = {-1e30f, -1e30f, -1e30f, -1e30f};
#pragma unroll
    for (int nt = 0; nt < 7; nt++)
#pragma unroll
      for (int r = 0; r < 4; r++) mx[r] = fmaxf(mx[r], s[nt][r]);
#pragma unroll
    for (int off = 1; off <= 8; off <<= 1)
#pragma unroll
      for (int r = 0; r < 4; r++) mx[r] = fmaxf(mx[r], __shfl_xor(mx[r], off, 64));
    float sum[4] = {0.f, 0.f, 0.f, 0.f};
#pragma unroll
    for (int nt = 0; nt < 7; nt++)
#pragma unroll
      for (int r = 0; r < 4; r++) {
        float e = __expf(s[nt][r] - mx[r]);
        s[nt][r] = e; sum[r] += e;
      }
#pragma unroll
    for (int off = 1; off <= 8; off <<= 1)
#pragma unroll
      for (int r = 0; r < 4; r++) sum[r] += __shfl_xor(sum[r], off, 64);
    float inv[4];
#pragma unroll
    for (int r = 0; r < 4; r++) inv[r] = 1.0f / sum[r];
    // P (C layout) -> per-wave LDS in A layout [m][k] (coalesced b16 writes)
#pragma unroll
    for (int nt = 0; nt < 7; nt++) {
      int colk = nt * 16 + l;
#pragma unroll
      for (int r = 0; r < 4; r++)
        PwW[(q * 4 + r) * 136 + colk] = f2bf(s[nt][r] * inv[r]);
    }
    asm volatile("s_waitcnt lgkmcnt(0)" ::: "memory");
    // PV: O(16x32) = P(16x128) @ V(128x32)
    f32x4 o0 = {0.f, 0.f, 0.f, 0.f}, o1 = {0.f, 0.f, 0.f, 0.f};
#pragma unroll
    for (int kt = 0; kt < 4; kt++) {
      short8 pa = *reinterpret_cast<const short8*>(&PwW[l * 136 + kt * 32 + q * 8]);
      short8 v0 = *reinterpret_cast<const short8*>(&Vtf[((kt * 4 + q) * 96 + h * 32 + l) * 8]);
      short8 v1 = *reinterpret_cast<const short8*>(&Vtf[((kt * 4 + q) * 96 + h * 32 + 16 + l) * 8]);
      o0 = __builtin_amdgcn_mfma_f32_16x16x32_bf16(pa, v0, o0, 0, 0, 0);
      o1 = __builtin_amdgcn_mfma_f32_16x16x32_bf16(pa, v1, o1, 0, 0, 0);
    }
    // O overwrites the (h,mt) Q slot — only this wave ever touches it
#pragma unroll
    for (int r = 0; r < 4; r++) {
      int tok = mt * 16 + q * 4 + r;
      if (tok < 98) {
        int ch0 = h * 32 + l;
        Qf[((ch0 >> 3) * 98 + tok) * 8 + (ch0 & 7)] = f2bf(o0[r]);
        int ch1 = h * 32 + 16 + l;
        Qf[((ch1 >> 3) * 98 + tok) * 8 + (ch1 & 7)] = f2bf(o1[r]);
      }
    }
  }
  __syncthreads();

  // ---- phase 3: proj = O(98x96) @ Wp^T(96x96) + b, scatter fp32 ----
  for (int t = wv; t < 42; t += 4) {          // 6 n-tiles x 7 m-tiles
    int nt = t / 7, mt = t - nt * 7;
    int n = nt * 16 + l;
    short8 b0 = *reinterpret_cast<const short8*>(wp + n * 96 +      q * 8);
    short8 b1 = *reinterpret_cast<const short8*>(wp + n * 96 + 32 + q * 8);
    short8 b2 = *reinterpret_cast<const short8*>(wp + n * 96 + 64 + q * 8);
    int arow = mt * 16 + l;
    short8 a0 = zero8, a1 = zero8, a2 = zero8;
    if (arow < 98) {
      a0 = *reinterpret_cast<const short8*>(&Qf[(( q    ) * 98 + arow) * 8]);
      a1 = *reinterpret_cast<const short8*>(&Qf[((4 + q ) * 98 + arow) * 8]);
      a2 = *reinterpret_cast<const short8*>(&Qf[((8 + q ) * 98 + arow) * 8]);
    }
    f32x4 acc = {0.f, 0.f, 0.f, 0.f};
    acc = __builtin_amdgcn_mfma_f32_16x16x32_bf16(a0, b0, acc, 0, 0, 0);
    acc = __builtin_amdgcn_mfma_f32_16x16x32_bf16(a1, b1, acc, 0, 0, 0);
    acc = __builtin_amdgcn_mfma_f32_16x16x32_bf16(a2, b2, acc, 0, 0, 0);
    float pb = proj_b[n];
#pragma unroll
    for (int r = 0; r < 4; r++) {
      int tok = mt * 16 + q * 4 + r;
      if (tok < 98) out[eoff[tok] + n] = acc[r] + pb;
    }
  }
}

extern "C" void kernel_launch(void* const* d_in, const int* in_sizes, int n_in,
                              void* d_out, int out_size, void* d_ws, size_t ws_size,
                              hipStream_t stream) {
  const float* x      = (const float*)d_in[0];
  const float* qkv_w  = (const float*)d_in[1];
  const float* qkv_b  = (const float*)d_in[2];
  const float* proj_w = (const float*)d_in[3];
  const float* proj_b = (const float*)d_in[4];
  const float* tbl    = (const float*)d_in[5];

  unsigned short* wq = (unsigned short*)d_ws;
  unsigned short* wp = wq + WQ_ELEMS;
  float* bias = (float*)((char*)d_ws + (WQ_ELEMS + WP_ELEMS) * 2);

  prep_kernel<<<(BIAS_ELEMS + 255) / 256, 256, 0, stream>>>(qkv_w, proj_w, tbl,
                                                            wq, wp, bias);
  winattn_kernel<<<4096, 256, 0, stream>>>(x, qkv_b, proj_b, wq, wp, bias,
                                           (float*)d_out);
}

// Round 3
// 542.164 us; speedup vs baseline: 1.6902x; 1.1333x over previous
//
#include <hip/hip_runtime.h>
#include <hip/hip_bf16.h>

// Fused 3D shifted-window attention, round 3: all four matmuls oriented so
// each lane's 4 C-values are CONTIGUOUS (channels or tokens) -> packed b64
// LDS writes / dwordx4 global stores instead of 4x scalar scatter.
// S/PV computed transposed: softmax owns one query row per lane (4 shuffles
// not 32; single 1/sum applied to O, not 28 P muls). Masking folded into the
// precomputed bias tensor (-1e30); exp -> exp2 with log2e folded into scale.

typedef __attribute__((ext_vector_type(8))) short short8;   // 8 bf16 = 4 VGPR
typedef __attribute__((ext_vector_type(4))) float f32x4;    // MFMA acc

#define WQ_ELEMS (288 * 96)
#define WP_ELEMS (96 * 96)
#define BIAS_ELEMS (3 * 112 * 112)
#define LOG2E 1.4426950408889634f

__device__ __forceinline__ unsigned short f2bf(float f) {
  __hip_bfloat16 h = __float2bfloat16(f);
  return *reinterpret_cast<unsigned short*>(&h);
}

// RNE bf16 pack of two floats -> one dword (a = low half). ~5 VALU.
__device__ __forceinline__ unsigned int pack_bf2(float a, float b) {
  unsigned ua = __float_as_uint(a), ub = __float_as_uint(b);
  ua += 0x7fffu + ((ua >> 16) & 1u);
  ub += 0x7fffu + ((ub >> 16) & 1u);
  return __builtin_amdgcn_perm(ub, ua, 0x07060302u);
}

__global__ __launch_bounds__(256) void prep_kernel(
    const float* __restrict__ qkv_w, const float* __restrict__ proj_w,
    const float* __restrict__ tbl, unsigned short* __restrict__ wq,
    unsigned short* __restrict__ wp, float* __restrict__ bias) {
  int i = blockIdx.x * 256 + threadIdx.x;
  if (i < WQ_ELEMS) wq[i] = f2bf(qkv_w[i]);
  if (i < WP_ELEMS) wp[i] = f2bf(proj_w[i]);
  if (i < BIAS_ELEMS) {
    int h = i / 12544; int rem = i - h * 12544;
    int m = rem / 112; int n = rem - m * 112;
    float v = -1e30f;                       // mask folded into bias
    if (m < 98 && n < 98) {
      int m0 = m / 49, mr = m - m0 * 49, m1 = mr / 7, m2 = mr - m1 * 7;
      int n0 = n / 49, nr = n - n0 * 49, n1 = nr / 7, n2 = nr - n1 * 7;
      int idx = (m0 - n0 + 1) * 169 + (m1 - n1 + 6) * 13 + (m2 - n2 + 6);
      v = tbl[idx * 3 + h] * LOG2E;         // exp2 domain
    }
    bias[i] = v;
  }
}

// LDS (ushort units):
//   Qf/O [12 cb][98 tok][8] : 9408  @ 0      (O overwrites Q in-place)
//   Kf   [12 cb][98 tok][8] : 9408  @ 9408
//   Vtf  [16 tb][96 ch][8]  : 12288 @ 18816  (tokens 112..127 zeroed;
//                                             98..111 finite garbage x P=0)
//   Xf/P [12 cb][98][8]=9408 vs 4 x [16 q][136 k]=8704 -> 9408 @ 31104
// total 81024 B + eoff = 81416 B -> 2 blocks/CU.

__global__ __launch_bounds__(256) void winattn_kernel(
    const float* __restrict__ x, const float* __restrict__ qkv_b,
    const float* __restrict__ proj_b, const unsigned short* __restrict__ wq,
    const unsigned short* __restrict__ wp, const float* __restrict__ bias,
    float* __restrict__ out) {

  __shared__ __align__(16) unsigned short lds[40512];
  __shared__ int eoff[98];

  unsigned short* Qf  = lds;          // also O
  unsigned short* Kf  = lds + 9408;
  unsigned short* Vtf = lds + 18816;
  unsigned short* Xf  = lds + 31104;  // also P (per-wave)

  const int tid  = threadIdx.x;
  const int wv   = tid >> 6;
  const int lane = tid & 63;
  const int l    = lane & 15;
  const int q    = lane >> 4;

  const short8 zero8 = {0, 0, 0, 0, 0, 0, 0, 0};

  int t1 = blockIdx.x;
  const int wb = t1 & 7;  t1 >>= 3;
  const int hb = t1 & 7;  t1 >>= 3;
  const int sb = t1 & 3;  t1 >>= 2;
  const int d2 = t1 & 1;  t1 >>= 1;
  const int d1 = t1 & 1;  t1 >>= 1;
  const int b  = t1;

  // ---- phase 0: zero Vtf tokens 112..127 (1536 us = 768 dwords) ----
  for (int i = tid; i < 768; i += 256)
    reinterpret_cast<unsigned*>(Vtf + 10752)[i] = 0;
  if (tid < 98) {
    int wi0 = tid / 49; int r = tid - wi0 * 49;
    int wi1 = r / 7;    int wi2 = r - wi1 * 7;
    int s  = sb * 2 + wi0;            int so = (s + 1) & 7;
    int hh = (hb * 2 + d1) * 7 + wi1; int ho = hh + 6; if (ho >= 112) ho -= 112;
    int ww = (wb * 2 + d2) * 7 + wi2; int wo = ww + 6; if (wo >= 112) wo -= 112;
    eoff[tid] = (b * 100352 + (so * 112 + ho) * 112 + wo) * 96;
  }
  __syncthreads();

  // ---- phase 1a: gather x rows -> Xf (bf16, fragment order) ----
  for (int i = tid; i < 2352; i += 256) {
    int row = i / 24, c4 = i - row * 24;
    float4 v = *reinterpret_cast<const float4*>(x + eoff[row] + c4 * 4);
    uint2 u;
    u.x = pack_bf2(v.x, v.y); u.y = pack_bf2(v.z, v.w);
    *reinterpret_cast<uint2*>(&Xf[((c4 >> 1) * 98 + row) * 8 + (c4 & 1) * 4]) = u;
  }
  __syncthreads();

  // ---- phase 1b-QK: A=Wqkv rows 0..191 (m=channel), B=X (n=token) ----
  const float qscale = 0.17677669529663687f * LOG2E;
  for (int t = wv; t < 84; t += 4) {          // 12 ch-tiles x 7 tok-tiles
    int ct = t / 7, tt = t - ct * 7;
    int mch = ct * 16 + l;
    short8 a0 = *reinterpret_cast<const short8*>(wq + mch * 96 +      q * 8);
    short8 a1 = *reinterpret_cast<const short8*>(wq + mch * 96 + 32 + q * 8);
    short8 a2 = *reinterpret_cast<const short8*>(wq + mch * 96 + 64 + q * 8);
    int tok = tt * 16 + l;
    short8 b0 = zero8, b1 = zero8, b2 = zero8;
    if (tok < 98) {
      b0 = *reinterpret_cast<const short8*>(&Xf[(( q    ) * 98 + tok) * 8]);
      b1 = *reinterpret_cast<const short8*>(&Xf[((4 + q ) * 98 + tok) * 8]);
      b2 = *reinterpret_cast<const short8*>(&Xf[((8 + q ) * 98 + tok) * 8]);
    }
    f32x4 acc = {0.f, 0.f, 0.f, 0.f};
    acc = __builtin_amdgcn_mfma_f32_16x16x32_bf16(a0, b0, acc, 0, 0, 0);
    acc = __builtin_amdgcn_mfma_f32_16x16x32_bf16(a1, b1, acc, 0, 0, 0);
    acc = __builtin_amdgcn_mfma_f32_16x16x32_bf16(a2, b2, acc, 0, 0, 0);
    float4 bv = *reinterpret_cast<const float4*>(qkv_b + ct * 16 + q * 4);
    bool isQ = (ct < 6);                       // wave-uniform
    float sc = isQ ? qscale : 1.0f;
    unsigned short* dst = isQ ? Qf : Kf;
    int c0 = (isQ ? ct * 16 : (ct - 6) * 16) + q * 4;
    uint2 pk;
    pk.x = pack_bf2((acc[0] + bv.x) * sc, (acc[1] + bv.y) * sc);
    pk.y = pack_bf2((acc[2] + bv.z) * sc, (acc[3] + bv.w) * sc);
    if (tok < 98)
      *reinterpret_cast<uint2*>(&dst[((c0 >> 3) * 98 + tok) * 8 + (c0 & 7)]) = pk;
  }

  // ---- phase 1b-V: A=X (m=token), B=Wqkv rows 192..287 (n=channel) ----
  for (int t = wv; t < 42; t += 4) {          // 6 ch-tiles x 7 tok-tiles
    int vt = t / 7, mt = t - vt * 7;
    int tokf = mt * 16 + l;
    short8 a0 = zero8, a1 = zero8, a2 = zero8;
    if (tokf < 98) {
      a0 = *reinterpret_cast<const short8*>(&Xf[(( q    ) * 98 + tokf) * 8]);
      a1 = *reinterpret_cast<const short8*>(&Xf[((4 + q ) * 98 + tokf) * 8]);
      a2 = *reinterpret_cast<const short8*>(&Xf[((8 + q ) * 98 + tokf) * 8]);
    }
    int ch = vt * 16 + l;                      // V channel 0..95
    short8 b0 = *reinterpret_cast<const short8*>(wq + (192 + ch) * 96 +      q * 8);
    short8 b1 = *reinterpret_cast<const short8*>(wq + (192 + ch) * 96 + 32 + q * 8);
    short8 b2 = *reinterpret_cast<const short8*>(wq + (192 + ch) * 96 + 64 + q * 8);
    f32x4 acc = {0.f, 0.f, 0.f, 0.f};
    acc = __builtin_amdgcn_mfma_f32_16x16x32_bf16(a0, b0, acc, 0, 0, 0);
    acc = __builtin_amdgcn_mfma_f32_16x16x32_bf16(a1, b1, acc, 0, 0, 0);
    acc = __builtin_amdgcn_mfma_f32_16x16x32_bf16(a2, b2, acc, 0, 0, 0);
    float bv = qkv_b[192 + ch];
    int tok0 = mt * 16 + q * 4;                // 4 consecutive tokens
    uint2 pk;
    pk.x = pack_bf2(acc[0] + bv, acc[1] + bv);
    pk.y = pack_bf2(acc[2] + bv, acc[3] + bv);
    // no mask: tokens 98..111 finite garbage, P columns there are zero
    *reinterpret_cast<uint2*>(&Vtf[((tok0 >> 3) * 96 + ch) * 8 + (tok0 & 7)]) = pk;
  }
  __syncthreads();

  // ---- phase 2: attention (transposed S and O) ----
  unsigned short* PwW = Xf + wv * 2176;        // [16 query][136: 128 key + pad]
  {                                            // zero key-pad cols 112..127
    int m = lane >> 2, cc = 112 + (lane & 3) * 4;
    uint2 z; z.x = 0; z.y = 0;
    *reinterpret_cast<uint2*>(&PwW[m * 136 + cc]) = z;
  }
  for (int p = wv; p < 21; p += 4) {
    int h = p / 7, mt = p - h * 7;
    int qtok = mt * 16 + l;                    // this lane's query row
    short8 qa = zero8;
    if (qtok < 98)
      qa = *reinterpret_cast<const short8*>(&Qf[((h * 4 + q) * 98 + qtok) * 8]);
    f32x4 s[7];
#pragma unroll
    for (int nt = 0; nt < 7; nt++) {
      int key = nt * 16 + l;
      short8 kb = zero8;
      if (key < 98)
        kb = *reinterpret_cast<const short8*>(&Kf[((h * 4 + q) * 98 + key) * 8]);
      f32x4 z = {0.f, 0.f, 0.f, 0.f};
      s[nt] = __builtin_amdgcn_mfma_f32_16x16x32_bf16(kb, qa, z, 0, 0, 0);
    }
    // bias (includes -1e30 masking), rows=key (quad), col=query (lane)
    const float* bh = bias + h * 12544 + qtok * 112 + q * 4;
#pragma unroll
    for (int nt = 0; nt < 7; nt++) {
      float4 bv = *reinterpret_cast<const float4*>(bh + nt * 16);
      s[nt][0] += bv.x; s[nt][1] += bv.y; s[nt][2] += bv.z; s[nt][3] += bv.w;
    }
    // softmax over this lane's query row: 28 local + 4-quad shuffle
    float mx = -3e38f;
#pragma unroll
    for (int nt = 0; nt < 7; nt++)
#pragma unroll
      for (int r = 0; r < 4; r++) mx = fmaxf(mx, s[nt][r]);
    mx = fmaxf(mx, __shfl_xor(mx, 16));
    mx = fmaxf(mx, __shfl_xor(mx, 32));
    float sum = 0.f;
#pragma unroll
    for (int nt = 0; nt < 7; nt++)
#pragma unroll
      for (int r = 0; r < 4; r++) {
        float e = exp2f(s[nt][r] - mx);
        s[nt][r] = e; sum += e;
      }
    sum += __shfl_xor(sum, 16);
    sum += __shfl_xor(sum, 32);
    float inv = __builtin_amdgcn_rcpf(sum);    // applied to O, not to P
    // store unnormalized P: [query l][key] -> 7 packed b64 writes
#pragma unroll
    for (int nt = 0; nt < 7; nt++) {
      uint2 pk;
      pk.x = pack_bf2(s[nt][0], s[nt][1]);
      pk.y = pack_bf2(s[nt][2], s[nt][3]);
      *reinterpret_cast<uint2*>(&PwW[l * 136 + nt * 16 + q * 4]) = pk;
    }
    asm volatile("s_waitcnt lgkmcnt(0)" ::: "memory");
    // O^T = V^T x P^T : A=Vtf (m=channel), B=P (n=query)
    f32x4 o0 = {0.f, 0.f, 0.f, 0.f}, o1 = {0.f, 0.f, 0.f, 0.f};
#pragma unroll
    for (int kt = 0; kt < 4; kt++) {
      short8 pa = *reinterpret_cast<const short8*>(&PwW[l * 136 + kt * 32 + q * 8]);
      short8 v0 = *reinterpret_cast<const short8*>(&Vtf[((kt * 4 + q) * 96 + h * 32 + l) * 8]);
      short8 v1 = *reinterpret_cast<const short8*>(&Vtf[((kt * 4 + q) * 96 + h * 32 + 16 + l) * 8]);
      o0 = __builtin_amdgcn_mfma_f32_16x16x32_bf16(v0, pa, o0, 0, 0, 0);
      o1 = __builtin_amdgcn_mfma_f32_16x16x32_bf16(v1, pa, o1, 0, 0, 0);
    }
    if (qtok < 98) {                           // 4 consecutive channels/lane
      int c0 = h * 32 + q * 4;
      uint2 pk0;
      pk0.x = pack_bf2(o0[0] * inv, o0[1] * inv);
      pk0.y = pack_bf2(o0[2] * inv, o0[3] * inv);
      *reinterpret_cast<uint2*>(&Qf[((c0 >> 3) * 98 + qtok) * 8 + (c0 & 7)]) = pk0;
      int c1 = c0 + 16;
      uint2 pk1;
      pk1.x = pack_bf2(o1[0] * inv, o1[1] * inv);
      pk1.y = pack_bf2(o1[2] * inv, o1[3] * inv);
      *reinterpret_cast<uint2*>(&Qf[((c1 >> 3) * 98 + qtok) * 8 + (c1 & 7)]) = pk1;
    }
  }
  __syncthreads();

  // ---- phase 3: proj, A=Wp (m=out-channel), B=O (n=token) ----
  for (int t = wv; t < 42; t += 4) {           // 6 ch-tiles x 7 tok-tiles
    int ct = t / 7, tt = t - ct * 7;
    int mch = ct * 16 + l;
    short8 a0 = *reinterpret_cast<const short8*>(wp + mch * 96 +      q * 8);
    short8 a1 = *reinterpret_cast<const short8*>(wp + mch * 96 + 32 + q * 8);
    short8 a2 = *reinterpret_cast<const short8*>(wp + mch * 96 + 64 + q * 8);
    int tok = tt * 16 + l;
    short8 b0 = zero8, b1 = zero8, b2 = zero8;
    if (tok < 98) {
      b0 = *reinterpret_cast<const short8*>(&Qf[(( q    ) * 98 + tok) * 8]);
      b1 = *reinterpret_cast<const short8*>(&Qf[((4 + q ) * 98 + tok) * 8]);
      b2 = *reinterpret_cast<const short8*>(&Qf[((8 + q ) * 98 + tok) * 8]);
    }
    f32x4 acc = {0.f, 0.f, 0.f, 0.f};
    acc = __builtin_amdgcn_mfma_f32_16x16x32_bf16(a0, b0, acc, 0, 0, 0);
    acc = __builtin_amdgcn_mfma_f32_16x16x32_bf16(a1, b1, acc, 0, 0, 0);
    acc = __builtin_amdgcn_mfma_f32_16x16x32_bf16(a2, b2, acc, 0, 0, 0);
    float4 pb = *reinterpret_cast<const float4*>(proj_b + ct * 16 + q * 4);
    if (tok < 98) {                            // one dwordx4 store per tile
      float4 o;
      o.x = acc[0] + pb.x; o.y = acc[1] + pb.y;
      o.z = acc[2] + pb.z; o.w = acc[3] + pb.w;
      *reinterpret_cast<float4*>(out + eoff[tok] + ct * 16 + q * 4) = o;
    }
  }
}

extern "C" void kernel_launch(void* const* d_in, const int* in_sizes, int n_in,
                              void* d_out, int out_size, void* d_ws, size_t ws_size,
                              hipStream_t stream) {
  const float* x      = (const float*)d_in[0];
  const float* qkv_w  = (const float*)d_in[1];
  const float* qkv_b  = (const float*)d_in[2];
  const float* proj_w = (const float*)d_in[3];
  const float* proj_b = (const float*)d_in[4];
  const float* tbl    = (const float*)d_in[5];

  unsigned short* wq = (unsigned short*)d_ws;
  unsigned short* wp = wq + WQ_ELEMS;
  float* bias = (float*)((char*)d_ws + (WQ_ELEMS + WP_ELEMS) * 2);

  prep_kernel<<<(BIAS_ELEMS + 255) / 256, 256, 0, stream>>>(qkv_w, proj_w, tbl,
                                                            wq, wp, bias);
  winattn_kernel<<<4096, 256, 0, stream>>>(x, qkv_b, proj_b, wq, wp, bias,
                                           (float*)d_out);
}